// Round 2
// baseline (370.612 us; speedup 1.0000x reference)
//
#include <hip/hip_runtime.h>

#define DHW   192
#define R     8
#define NPTS  16

typedef float f32x4 __attribute__((ext_vector_type(4)));

// ---------------------------------------------------------------------------
// Kernel 1: pure streaming zero-fill of the whole output (click_map pos/neg +
// dense_embeddings). 99.6% of the output is zero; make the hot path literally
// a memset. 2048 blocks x 256 threads, grid-stride, nontemporal float4 stores
// (340 MB is >> 32 MB L2; don't write-allocate).
// ---------------------------------------------------------------------------
__global__ __launch_bounds__(256) void zero_kernel(f32x4* __restrict__ out,
                                                   size_t n4)
{
    size_t i = (size_t)blockIdx.x * 256 + threadIdx.x;
    const size_t stride = (size_t)gridDim.x * 256;
    const f32x4 z = {0.f, 0.f, 0.f, 0.f};
    for (; i < n4; i += stride)
        __builtin_nontemporal_store(z, out + i);
}

// ---------------------------------------------------------------------------
// Kernel 2: paint the 17^3 Gaussian cubes. One block per (batch, point).
// Last-writer-wins per (channel, voxel): a voxel is written by point j only
// if no later point j' > j with the same channel covers it (the reference's
// sequential dynamic_update_slice semantics — including the kernel's zeroed
// corners, r2 >= 128, which DO overwrite earlier values).
// ~64 * 4913 voxels = ~1.3 MB of writes: negligible next to the zero-fill.
// ---------------------------------------------------------------------------
__global__ __launch_bounds__(256) void paint_kernel(
    const float* __restrict__ coords,   // (4,16,3) float32: x,y,z
    const int*   __restrict__ labels,   // (4,16) int32 in {-1,0,1}
    float*       __restrict__ out)
{
    const int b = blockIdx.x / NPTS;
    const int j = blockIdx.x % NPTS;
    const int lab = labels[b * NPTS + j];
    if (lab != 0 && lab != 1) return;   // l == -1 writes nothing

    const int px = (int)coords[(b * NPTS + j) * 3 + 0];
    const int py = (int)coords[(b * NPTS + j) * 3 + 1];
    const int pz = (int)coords[(b * NPTS + j) * 3 + 2];

    // Shared list of LATER points of this batch on the SAME channel
    // (static-indexed via shared mem; per-thread runtime-indexed arrays
    // would spill to scratch).
    __shared__ int slx[NPTS], sly[NPTS], slz[NPTS];
    __shared__ int snl;
    if (threadIdx.x == 0) {
        int nl = 0;
        for (int j2 = j + 1; j2 < NPTS; ++j2) {
            if (labels[b * NPTS + j2] == lab) {
                slx[nl] = (int)coords[(b * NPTS + j2) * 3 + 0];
                sly[nl] = (int)coords[(b * NPTS + j2) * 3 + 1];
                slz[nl] = (int)coords[(b * NPTS + j2) * 3 + 2];
                ++nl;
            }
        }
        snl = nl;
    }
    __syncthreads();
    const int nl = snl;

    const int ch = (lab == 1) ? 0 : 1;  // pos channel first, then neg
    const size_t vol = (size_t)DHW * DHW * DHW;
    float* __restrict__ dst = out + (size_t)(b * 2 + ch) * vol;

    for (int t = threadIdx.x; t < 17 * 17 * 17; t += 256) {
        const int dz  = t / 289;            // 289 = 17*17
        const int rem = t - dz * 289;
        const int dy  = rem / 17;
        const int dx  = rem - dy * 17;
        const int z = pz + dz - R;          // unpadded (cropped) coords
        const int y = py + dy - R;
        const int x = px + dx - R;
        if ((unsigned)z >= DHW || (unsigned)y >= DHW || (unsigned)x >= DHW)
            continue;                       // falls in the pad region -> cropped
        bool stolen = false;
        for (int k = 0; k < nl; ++k) {
            if (abs(z - slz[k]) <= R && abs(y - sly[k]) <= R &&
                abs(x - slx[k]) <= R) { stolen = true; break; }
        }
        if (stolen) continue;               // a later point rewrites this voxel
        const int rz = dz - R, ry = dy - R, rx = dx - R;
        const int r2 = rz * rz + ry * ry + rx * rx;
        // reference zeroes entries with h < eps*h.max()  <=>  r2 >= 128
        const float v = (r2 >= 128) ? 0.f : __expf((float)r2 * -0.125f);
        dst[((size_t)z * DHW + y) * DHW + x] = v;
    }
}

extern "C" void kernel_launch(void* const* d_in, const int* in_sizes, int n_in,
                              void* d_out, int out_size, void* d_ws, size_t ws_size,
                              hipStream_t stream) {
    const float* coords = (const float*)d_in[0];  // 4*16*3 floats
    const int*   labels = (const int*)d_in[1];    // 4*16 ints
    float*       out    = (float*)d_out;          // 12*192^3 floats

    const size_t n4 = (size_t)12 * DHW * DHW * DHW / 4;  // float4 count
    zero_kernel<<<2048, 256, 0, stream>>>((f32x4*)out, n4);
    paint_kernel<<<4 * NPTS, 256, 0, stream>>>(coords, labels, out);
}

// Round 3
// 338.380 us; speedup vs baseline: 1.0953x; 1.0953x over previous
//
#include <hip/hip_runtime.h>

#define DHW   192
#define R     8
#define NPTS  16

// Block: 192 threads = 4 y-rows x 48 float4-wide x positions.
// Grid:  bs * 192 (z) * 48 (y-quads) = 36864 blocks.
//
// Key structure: issue ALL zero stores first (no data dependency, so the
// write traffic starts draining at cycle ~0), THEN do the point staging /
// ballot / barrier. Blocks whose tile intersects a Gaussian cube recompute
// and overwrite pos/neg (same-thread same-address store -> program ordered,
// no race). 99.6% of blocks are pure memset with zero dead prologue time.
__global__ __launch_bounds__(192) void clickmap_kernel(
    const float* __restrict__ coords,   // (4,16,3) float32: x,y,z
    const int*   __restrict__ labels,   // (4,16) int32 in {-1,0,1}
    float*       __restrict__ out)      // 12*192^3 floats
{
    const int bid = blockIdx.x;
    const int yq  = bid % 48;
    const int z   = (bid / 48) % DHW;
    const int b   = bid / (48 * DHW);
    const int tid = threadIdx.x;
    const int row = tid / 48;        // 0..3
    const int xi  = tid % 48;        // 0..47
    const int y   = yq * 4 + row;
    const int x0  = xi * 4;

    const size_t vol  = (size_t)DHW * DHW * DHW;
    const size_t posi = (((size_t)(b * 2 + 0) * DHW + z) * DHW + y) * DHW + x0;
    const size_t negi = posi + vol;
    const size_t deni = (size_t)8 * vol + ((((size_t)b * DHW + z) * DHW + y) * DHW + x0);

    // --- phase 0: unconditional zero-fill, issued before any load dep ---
    const float4 zero4 = make_float4(0.f, 0.f, 0.f, 0.f);
    *(float4*)(out + deni) = zero4;     // dense_embeddings: always zero
    *(float4*)(out + posi) = zero4;
    *(float4*)(out + negi) = zero4;

    // --- phase 1: stage points + candidate mask (overlaps store drain) ---
    __shared__ int s_px[NPTS], s_py[NPTS], s_pz[NPTS], s_lab[NPTS];
    __shared__ unsigned s_mask;

    if (tid < 64) {
        bool cand = false;
        if (tid < NPTS) {
            const int j   = tid;
            const int lab = labels[b * NPTS + j];
            const int px  = (int)coords[(b * NPTS + j) * 3 + 0];
            const int py  = (int)coords[(b * NPTS + j) * 3 + 1];
            const int pz  = (int)coords[(b * NPTS + j) * 3 + 2];
            s_px[j] = px; s_py[j] = py; s_pz[j] = pz; s_lab[j] = lab;
            const int y0 = yq * 4;
            cand = (lab == 0 || lab == 1) &&
                   (pz >= z - R  && pz <= z + R) &&
                   (py >= y0 - R && py <= y0 + 3 + R);
        }
        unsigned long long m = __ballot(cand);
        if (tid == 0) s_mask = (unsigned)m;
    }
    __syncthreads();

    const unsigned mask = s_mask;
    if (mask == 0u) return;             // common path: done (pure memset)

    // --- phase 2: rare path — recompute and overwrite pos/neg tiles ---
    float pv[4] = {0.f, 0.f, 0.f, 0.f};
    float nv[4] = {0.f, 0.f, 0.f, 0.f};
    bool  fp[4] = {false, false, false, false};
    bool  fn[4] = {false, false, false, false};

    // Reverse scan over this batch's points: last writer in the reference's
    // sequential scan wins, per channel, per voxel.
    for (int j = NPTS - 1; j >= 0; --j) {
        if (!((mask >> j) & 1u)) continue;
        const int lab = s_lab[j];
        const int dz  = z + R - s_pz[j];
        const int dy  = y + R - s_py[j];
        if ((unsigned)dz > 16u || (unsigned)dy > 16u) continue;
        const int rz = dz - R, ry = dy - R;
        const int r2yz = rz * rz + ry * ry;
        #pragma unroll
        for (int e = 0; e < 4; ++e) {
            const int dx = x0 + e + R - s_px[j];
            if ((unsigned)dx > 16u) continue;
            const int rx = dx - R;
            const int r2 = r2yz + rx * rx;
            // reference zeroes entries with h < eps*h.max()  <=>  r2 >= 128
            const float v = (r2 >= 128) ? 0.f : __expf((float)r2 * -0.125f);
            if (lab == 1) { if (!fp[e]) { pv[e] = v; fp[e] = true; } }
            else          { if (!fn[e]) { nv[e] = v; fn[e] = true; } }
        }
    }

    *(float4*)(out + posi) = make_float4(pv[0], pv[1], pv[2], pv[3]);
    *(float4*)(out + negi) = make_float4(nv[0], nv[1], nv[2], nv[3]);
}

extern "C" void kernel_launch(void* const* d_in, const int* in_sizes, int n_in,
                              void* d_out, int out_size, void* d_ws, size_t ws_size,
                              hipStream_t stream) {
    const float* coords = (const float*)d_in[0];  // 4*16*3 floats
    const int*   labels = (const int*)d_in[1];    // 4*16 ints
    float*       out    = (float*)d_out;          // 12*192^3 floats

    const int grid = 4 * DHW * 48;                // 36864 blocks
    clickmap_kernel<<<grid, 192, 0, stream>>>(coords, labels, out);
}